// Round 4
// baseline (329.341 us; speedup 1.0000x reference)
//
#include <hip/hip_runtime.h>
#include <hip/hip_fp16.h>
#include <hip/hip_bf16.h>

// PGNN layer for MI355X (gfx950).
//   u = feature @ W_u + b_u            [N,64]
//   v = feature @ W_v + b_v            [N,64]
//   msg[e] = v[dst[e]] + u[src[e]] * sp_dist[e]
//   msgs = relu(msg[anchor_eid]).reshape(N, K, 64)
//   out_position  = msgs @ W_out + b_out   -> [N,K]
//   out_structure = mean_k(msgs)           -> [N,64]
// N=50000, K=64, E=N*K=3.2M, IN_DIM=256, OUT_DIM=64.
// d_out = out_position (N*K floats) ++ out_structure (N*64 floats)
//
// R4 change vs R3: edge kernel software-pipelines the row gathers.
// R3 evidence: effective BW pinned at 3.6 TB/s (45% peak) across two different
// structures, occupancy 40%, VALUBusy 21% -> latency-bound, ~1 outstanding
// line/wave (Little's law). Fix: double-buffer the 32 gathers per 16-k chunk
// in registers; issue chunk c+1's loads BEFORE computing chunk c. lgkm-only
// waits keep vmcnt loads in flight across the LDS transpose/reduce.

#define IN_DIM 256
#define OUT_DIM 64
#define KANCH 64

// ---------------- Kernel 1: fused projection GEMM (fp32 -> fp16 uv) --------
// uv[N][128]: cols 0..63 = u_feat, cols 64..127 = v_feat (as __half).
// BM=64 nodes, BN=128 cols, BK=16. 128 threads; each computes 8x8.
__global__ __launch_bounds__(128) void pgnn_proj_kernel(
    const float* __restrict__ feature,
    const float* __restrict__ Wu, const float* __restrict__ bu,
    const float* __restrict__ Wv, const float* __restrict__ bv,
    __half* __restrict__ uv, int N)
{
    constexpr int BM = 64, BK = 16, PA = 68, PB = 132;
    __shared__ float sA[BK * PA];   // sA[k][m], transposed A tile
    __shared__ float sB[BK * PB];   // sB[k][c]

    const int tid  = threadIdx.x;
    const int row0 = blockIdx.x * BM;
    const int tr   = tid >> 4;   // 0..7 -> rows tr*8..tr*8+7
    const int tc   = tid & 15;   // 0..15 -> cols tc*8..tc*8+7

    float acc[8][8];
    #pragma unroll
    for (int i = 0; i < 8; ++i)
        #pragma unroll
        for (int j = 0; j < 8; ++j) acc[i][j] = 0.f;

    for (int k0 = 0; k0 < IN_DIM; k0 += BK) {
        #pragma unroll
        for (int i = 0; i < 2; ++i) {
            int f  = tid + i * 128;        // 0..255
            int m  = f >> 2, c4 = f & 3;
            int gr = row0 + m;
            float4 va = make_float4(0.f, 0.f, 0.f, 0.f);
            if (gr < N)
                va = *reinterpret_cast<const float4*>(
                        &feature[(size_t)gr * IN_DIM + k0 + c4 * 4]);
            sA[(c4 * 4 + 0) * PA + m] = va.x;
            sA[(c4 * 4 + 1) * PA + m] = va.y;
            sA[(c4 * 4 + 2) * PA + m] = va.z;
            sA[(c4 * 4 + 3) * PA + m] = va.w;
        }
        #pragma unroll
        for (int i = 0; i < 4; ++i) {
            int f  = tid + i * 128;        // 0..511
            int kk = f >> 5, c4 = f & 31;
            float4 vb;
            if (c4 < 16)
                vb = *reinterpret_cast<const float4*>(&Wu[(k0 + kk) * OUT_DIM + c4 * 4]);
            else
                vb = *reinterpret_cast<const float4*>(&Wv[(k0 + kk) * OUT_DIM + (c4 - 16) * 4]);
            *reinterpret_cast<float4*>(&sB[kk * PB + c4 * 4]) = vb;
        }
        __syncthreads();

        #pragma unroll
        for (int k = 0; k < BK; ++k) {
            float4 a0 = *reinterpret_cast<const float4*>(&sA[k * PA + tr * 8]);
            float4 a1 = *reinterpret_cast<const float4*>(&sA[k * PA + tr * 8 + 4]);
            float4 b0 = *reinterpret_cast<const float4*>(&sB[k * PB + tc * 8]);
            float4 b1 = *reinterpret_cast<const float4*>(&sB[k * PB + tc * 8 + 4]);
            float a[8] = {a0.x, a0.y, a0.z, a0.w, a1.x, a1.y, a1.z, a1.w};
            float b[8] = {b0.x, b0.y, b0.z, b0.w, b1.x, b1.y, b1.z, b1.w};
            #pragma unroll
            for (int i = 0; i < 8; ++i)
                #pragma unroll
                for (int j = 0; j < 8; ++j)
                    acc[i][j] = fmaf(a[i], b[j], acc[i][j]);
        }
        __syncthreads();
    }

    #pragma unroll
    for (int i = 0; i < 8; ++i) {
        int gr = row0 + tr * 8 + i;
        if (gr >= N) continue;
        #pragma unroll
        for (int j = 0; j < 8; j += 2) {
            int c0 = tc * 8 + j;
            float bias0 = (c0 < OUT_DIM) ? bu[c0] : bv[c0 - OUT_DIM];
            float bias1 = (c0 + 1 < OUT_DIM) ? bu[c0 + 1] : bv[c0 + 1 - OUT_DIM];
            __half2 h = __floats2half2_rn(acc[i][j] + bias0, acc[i][j + 1] + bias1);
            *reinterpret_cast<__half2*>(&uv[(size_t)gr * 128 + c0]) = h;
        }
    }
}

// ---------------- Kernel 2: anchor gather / message / outputs ---------------
// One 64-lane wave per node, lane = dim d. 4 waves/block.
// K in 4 chunks of 16, double-buffered: issue chunk c+1's 32 row-gathers
// (register destinations, static indices) before computing chunk c.
#define TPAD 67
__global__ __launch_bounds__(256) void pgnn_edge_kernel(
    const __half* __restrict__ uv,
    const int*    __restrict__ src,
    const int*    __restrict__ dst,
    const float*  __restrict__ sp_dist,
    const int*    __restrict__ anchor_eid,
    const float*  __restrict__ W_out,
    const float*  __restrict__ b_out,
    float* __restrict__ out_pos,     // [N,64]
    float* __restrict__ out_struct,  // [N,64]
    int N)
{
    const int lane = threadIdx.x & 63;
    const int wv   = threadIdx.x >> 6;
    const int n    = blockIdx.x * 4 + wv;
    if (n >= N) return;   // wave-uniform; no block-wide syncs below

    __shared__ float tile[4][16 * TPAD];
    float* t = tile[wv];

    const int   e     = anchor_eid[(size_t)n * KANCH + lane];
    const int   s_my  = src[e];
    const int   d_my  = dst[e];
    const float sp_my = sp_dist[e];

    const float w  = W_out[lane];
    const float bo = b_out[0];

    float acc = 0.f;

    __half ub[2][16];   // double-buffered u gathers (chunk of 16 k's)
    __half vb[2][16];   // double-buffered v gathers

    // Prologue: issue chunk 0's 32 gathers.
    #pragma unroll
    for (int kk = 0; kk < 16; ++kk) {
        const int ss = __builtin_amdgcn_readlane(s_my, kk);
        const int dd = __builtin_amdgcn_readlane(d_my, kk);
        ub[0][kk] = uv[(size_t)ss * 128 + lane];
        vb[0][kk] = uv[(size_t)dd * 128 + 64 + lane];
    }

    #pragma unroll
    for (int c = 0; c < 4; ++c) {        // c compile-time after unroll
        const int cur = c & 1, nxt = cur ^ 1;

        // Issue next chunk's gathers before touching current chunk's data.
        if (c < 3) {
            #pragma unroll
            for (int kk = 0; kk < 16; ++kk) {
                const int k  = (c + 1) * 16 + kk;
                const int ss = __builtin_amdgcn_readlane(s_my, k);
                const int dd = __builtin_amdgcn_readlane(d_my, k);
                ub[nxt][kk] = uv[(size_t)ss * 128 + lane];
                vb[nxt][kk] = uv[(size_t)dd * 128 + 64 + lane];
            }
        }

        // Pass 1: message + struct-acc + LDS store of p = relu(m)*w[lane].
        #pragma unroll
        for (int kk = 0; kk < 16; ++kk) {
            const int k = c * 16 + kk;
            const float sp = __int_as_float(
                __builtin_amdgcn_readlane(__float_as_int(sp_my), k));
            const float u = __half2float(ub[cur][kk]);
            const float v = __half2float(vb[cur][kk]);
            float m = fmaxf(fmaf(u, sp, v), 0.f);
            acc += m;
            t[kk * TPAD + lane] = m * w;
        }
        asm volatile("s_waitcnt lgkmcnt(0)" ::: "memory");

        // Pass 2: pos[k = c*16 + r] = sum_d t[r][d]; lane (r,q) sums 16 d's.
        const int r = lane & 15, q = lane >> 4;
        float s = 0.f;
        #pragma unroll
        for (int j = 0; j < 16; ++j) s += t[r * TPAD + q * 16 + j];
        s += __shfl_xor(s, 16);
        s += __shfl_xor(s, 32);
        if (q == c) out_pos[(size_t)n * KANCH + lane] = s + bo;  // k == lane
        asm volatile("s_waitcnt lgkmcnt(0)" ::: "memory");
    }

    out_struct[(size_t)n * OUT_DIM + lane] = acc * (1.f / (float)KANCH);
}

extern "C" void kernel_launch(void* const* d_in, const int* in_sizes, int n_in,
                              void* d_out, int out_size, void* d_ws, size_t ws_size,
                              hipStream_t stream) {
    const float* feature    = (const float*)d_in[0];
    const int*   src        = (const int*)  d_in[1];
    const int*   dst        = (const int*)  d_in[2];
    const float* sp_dist    = (const float*)d_in[3];
    const int*   anchor_eid = (const int*)  d_in[4];
    // d_in[5] = dists_max: shape-only in the reference, numerically unused.
    const float* W_u   = (const float*)d_in[6];
    const float* b_u   = (const float*)d_in[7];
    const float* W_v   = (const float*)d_in[8];
    const float* b_v   = (const float*)d_in[9];
    const float* W_out = (const float*)d_in[10];
    const float* b_out = (const float*)d_in[11];

    const int N = in_sizes[0] / IN_DIM;           // 50000
    __half* uv = (__half*)d_ws;                   // [N][128] fp16, 12.8 MB

    float* out_pos    = (float*)d_out;            // [N,K]
    float* out_struct = (float*)d_out + (size_t)N * KANCH;

    {
        constexpr int BM = 64;
        dim3 grid((N + BM - 1) / BM);
        pgnn_proj_kernel<<<grid, 128, 0, stream>>>(feature, W_u, b_u, W_v, b_v, uv, N);
    }
    {
        dim3 grid((N + 3) / 4);
        pgnn_edge_kernel<<<grid, 256, 0, stream>>>(uv, src, dst, sp_dist, anchor_eid,
                                                   W_out, b_out, out_pos, out_struct, N);
    }
}